// Round 10
// baseline (1245.135 us; speedup 1.0000x reference)
//
#include <hip/hip_runtime.h>
#include <hip/hip_bf16.h>

// Self-attention: context = softmax((X@Wq)(X@Wk)^T / sqrt(d)) @ X
// N=8192, d=1024, fp32. Near-one-hot scores => fp32-grade score accuracy:
// f16 split (hi+lo, 3-term Ootomo) MFMA GEMMs for projections and QK^T;
// plain f16 MFMA for P@V.
//
// R10: per-chunk PV fused INTO the next chunk's S-GEMM launch. softmax(c)
//      completes whole P rows of chunk c, so PV(c) is ready immediately;
//      appended PV blocks (88) co-reside with SG blocks (704) and fill the
//      idle matrix-pipe slots (SG alone = 46% MfmaUtil). PV drops split-K
//      (partials would alias live K-splits) -> full-K, writes out directly;
//      add_rows + PK buffers eliminated. R9's ping-pong removed (it halved
//      chunks -> 1.5 blocks/CU GEMM starvation, +65 us).

typedef _Float16 f16x8 __attribute__((ext_vector_type(8)));
typedef float    f32x4 __attribute__((ext_vector_type(4)));

#define TM 128
#define TN 128

// async global->LDS, 16 B per lane; LDS dest = wave-uniform base + lane*16
__device__ __forceinline__ void g2lds16(const _Float16* g, _Float16* l) {
    __builtin_amdgcn_global_load_lds(
        (__attribute__((address_space(1))) unsigned int*)(g),
        (__attribute__((address_space(3))) unsigned int*)(l),
        16, 0, 0);
}

// ---------------------------------------------------------------- helpers

// one pass over X: write Xhi/Xlo (row-major split) and XT (f16 transpose)
__global__ void prep_x(const float* __restrict__ src,
                       _Float16* __restrict__ hi, _Float16* __restrict__ lo,
                       _Float16* __restrict__ xt, int R, int C) {
    __shared__ float tile[32][33];
    int c0 = blockIdx.x * 32, r0 = blockIdx.y * 32;
    int tx = threadIdx.x, ty = threadIdx.y;   // (32, 8)
#pragma unroll
    for (int k = 0; k < 4; ++k) {
        int r = ty + 8 * k;
        size_t idx = (size_t)(r0 + r) * C + c0 + tx;
        float v = src[idx];
        tile[r][tx] = v;
        _Float16 h = (_Float16)v;
        hi[idx] = h;
        lo[idx] = (_Float16)(v - (float)h);
    }
    __syncthreads();
#pragma unroll
    for (int k = 0; k < 4; ++k) {
        float v = tile[tx][ty + 8 * k];
        xt[(size_t)(c0 + ty + 8 * k) * R + r0 + tx] = (_Float16)v;
    }
}

// dst[c][r] = src[r][c] with f16 hi/lo split; z selects (Wq,Wk) source and
// shifts the dst by zOff elements (both hi and lo shift together).
__global__ void transpose_split2(const float* __restrict__ srcQ,
                                 const float* __restrict__ srcK,
                                 _Float16* __restrict__ dhi,
                                 _Float16* __restrict__ dlo,
                                 int R, int C, long zOff) {
    __shared__ float tile[32][33];
    const float* src = blockIdx.z ? srcK : srcQ;
    _Float16* hi = dhi + blockIdx.z * zOff;
    _Float16* lo = dlo + blockIdx.z * zOff;
    int c0 = blockIdx.x * 32, r0 = blockIdx.y * 32;
    int tx = threadIdx.x, ty = threadIdx.y;   // (32, 8)
#pragma unroll
    for (int k = 0; k < 4; ++k)
        tile[ty + 8 * k][tx] = src[(size_t)(r0 + ty + 8 * k) * C + c0 + tx];
    __syncthreads();
#pragma unroll
    for (int k = 0; k < 4; ++k) {
        float v = tile[tx][ty + 8 * k];
        _Float16 h = (_Float16)v;
        size_t idx = (size_t)(c0 + ty + 8 * k) * R + r0 + tx;
        hi[idx] = h;
        lo[idx] = (_Float16)(v - (float)h);
    }
}

// ---------------------------------------------------------------- GEMM core
// C[M,N] fp32 = sum_k A[M,K] * B_bt[N,K]^T (row-major; B transposed form).
// TERMS==3: A = Ahi+Alo, B = Bhi+Blo, compute hh + hl + lh (Ootomo 3-term).
// SPLIT_OUT==1: epilogue stores f16 hi/lo pair instead of fp32.
// BKH: k-step in halves (32 or 64); LDS rows XOR-swizzled (0-conflict,
// measured R6/R8). LDS requirement: exactly 16384 halves for both configs.
template <int TERMS, int SPLIT_OUT, int BKH>
__device__ __forceinline__ void gemm_core(
    const _Float16* __restrict__ Ahi, const _Float16* __restrict__ Alo,
    const _Float16* __restrict__ Bhi, const _Float16* __restrict__ Blo,
    float* __restrict__ C, _Float16* __restrict__ Chi,
    _Float16* __restrict__ Clo,
    long lda, long ldb, long ldc, int K,
    long rowBase, long colBase, _Float16* s) {
    const int t = threadIdx.x;
    const int wave = t >> 6;
    const int lane = t & 63;
    const int lm = lane & 15;     // row/col within 16-tile
    const int lq = lane >> 4;     // quad 0..3
    const int wr = wave >> 1;     // wave row 0..1
    const int wc = wave & 1;      // wave col 0..1

    // --- staging assignment (per wave) ---
    const _Float16* src;
    long myLd, gRow0;
    int ldsBaseH;
    if constexpr (TERMS == 3) {
        // wave 0: Ahi  1: Alo  2: Bhi  3: Blo ; 128 rows each
        const _Float16* a = (wave & 1) ? Alo : Ahi;
        const _Float16* b = (wave & 1) ? Blo : Bhi;
        src = (wave & 2) ? b : a;
        myLd = (wave & 2) ? ldb : lda;
        gRow0 = (wave & 2) ? colBase : rowBase;
        ldsBaseH = wave * (128 * BKH);
    } else {
        // wave 0: A rows 0-63  1: A rows 64-127  2: B 0-63  3: B 64-127
        src = (wave & 2) ? Bhi : Ahi;
        myLd = (wave & 2) ? ldb : lda;
        gRow0 = ((wave & 2) ? colBase : rowBase) + (wave & 1) * 64;
        ldsBaseH = (wave >> 1) * (128 * BKH) + (wave & 1) * (64 * BKH);
    }
    constexpr int LPR = BKH / 8;          // lanes per row: 4 or 8
    constexpr int RPI = 64 / LPR;         // rows per 1KB issue: 16 or 8
    constexpr int NISS = (TERMS == 3 ? 128 : 64) / RPI;   // 8 both ways
    const int lr = lane / LPR;            // row within issue
    const int slot = lane % LPR;          // 16B column slot
    // XOR swizzle: LDS[row][slot] holds global col group slot^swz(row);
    // issues stride RPI rows -> swz is lane-invariant across issues.
    const int swzW = (BKH == 32) ? ((lr >> 1) & 3) : (lr & 7);
    const _Float16* rp = src + (gRow0 + lr) * myLd + (slot ^ swzW) * 8;
    _Float16* ldsW = &s[ldsBaseH];

    const _Float16* sAh = s;
    const _Float16* sBh = s + (TERMS == 3 ? 2 : 1) * 128 * BKH;
    const _Float16* sAl = s + 128 * BKH;       // TERMS==3 only
    const _Float16* sBl = s + 3 * 128 * BKH;   // TERMS==3 only

    const int swzR = (BKH == 32) ? ((lm >> 1) & 3) : (lm & 7);

    f32x4 acc[4][4];
#pragma unroll
    for (int r = 0; r < 4; ++r)
#pragma unroll
        for (int c = 0; c < 4; ++c)
#pragma unroll
            for (int i = 0; i < 4; ++i) acc[r][c][i] = 0.0f;

    for (int k0 = 0; k0 < K; k0 += BKH) {
        __syncthreads();   // LDS safe to overwrite
#pragma unroll
        for (int j = 0; j < NISS; ++j)
            g2lds16(rp + (long)(j * RPI) * myLd + k0, ldsW + j * 512);
        __syncthreads();   // drains vmcnt before barrier => data visible

#pragma unroll
        for (int kk = 0; kk < BKH; kk += 32) {
            const int gb = kk >> 3;   // column-group base (8 halves/group)
            f16x8 ah[4], bh[4], al[4], bl[4];
#pragma unroll
            for (int r = 0; r < 4; ++r) {
                int ra = (wr * 64 + r * 16 + lm) * BKH + ((gb + lq) ^ swzR) * 8;
                int rb = (wc * 64 + r * 16 + lm) * BKH + ((gb + lq) ^ swzR) * 8;
                ah[r] = *(const f16x8*)&sAh[ra];
                bh[r] = *(const f16x8*)&sBh[rb];
                if constexpr (TERMS == 3) {
                    al[r] = *(const f16x8*)&sAl[ra];
                    bl[r] = *(const f16x8*)&sBl[rb];
                }
            }
#pragma unroll
            for (int r = 0; r < 4; ++r)
#pragma unroll
                for (int c = 0; c < 4; ++c) {
                    acc[r][c] = __builtin_amdgcn_mfma_f32_16x16x32_f16(
                        ah[r], bh[c], acc[r][c], 0, 0, 0);
                    if constexpr (TERMS == 3) {
                        acc[r][c] = __builtin_amdgcn_mfma_f32_16x16x32_f16(
                            ah[r], bl[c], acc[r][c], 0, 0, 0);
                        acc[r][c] = __builtin_amdgcn_mfma_f32_16x16x32_f16(
                            al[r], bh[c], acc[r][c], 0, 0, 0);
                    }
                }
        }
    }

    // C/D layout: col = lane&15, row = quad*4 + reg  (verified m89/m91)
#pragma unroll
    for (int r = 0; r < 4; ++r)
#pragma unroll
        for (int c = 0; c < 4; ++c)
#pragma unroll
            for (int i = 0; i < 4; ++i) {
                long row = rowBase + wr * 64 + r * 16 + lq * 4 + i;
                long col = colBase + wc * 64 + c * 16 + lm;
                if constexpr (SPLIT_OUT) {
                    float v = acc[r][c][i];
                    _Float16 h = (_Float16)v;
                    Chi[row * ldc + col] = h;
                    Clo[row * ldc + col] = (_Float16)(v - (float)h);
                } else {
                    C[row * ldc + col] = acc[r][c][i];
                }
            }
}

// Generic wrapper (projections, plan-B): SWAP==1 -> blockIdx.x = row-blocks
// (A-reuse XCD-co-located); gridDim.z slices via element offsets zA/zB/zC.
template <int TERMS, int SPLIT_OUT, int SWAP, int BKH>
__global__ __launch_bounds__(256, 4) void gemm_bt(
    const _Float16* __restrict__ Ahi, const _Float16* __restrict__ Alo,
    const _Float16* __restrict__ Bhi, const _Float16* __restrict__ Blo,
    float* __restrict__ C, _Float16* __restrict__ Chi, _Float16* __restrict__ Clo,
    long lda, long ldb, long ldc, int K, long zA, long zB, long zC) {
    __shared__ __align__(16) _Float16 s[16384];
    const long z = blockIdx.z;
    Ahi += z * zA;
    Bhi += z * zB;
    if constexpr (TERMS == 3) { Alo += z * zA; Blo += z * zB; }
    if constexpr (SPLIT_OUT) { Chi += z * zC; Clo += z * zC; }
    else C += z * zC;
    const long rowBase = (long)(SWAP ? blockIdx.x : blockIdx.y) * TM;
    const long colBase = (long)(SWAP ? blockIdx.y : blockIdx.x) * TN;
    gemm_core<TERMS, SPLIT_OUT, BKH>(Ahi, Alo, Bhi, Blo, C, Chi, Clo,
                                     lda, ldb, ldc, K, rowBase, colBase, s);
}

// Fused chunk kernel: blocks with by < gemmY run S = Q@K^T (TERMS=3,
// BKH=32, SWAP=0: grid.x = 64 col-blocks, K-splits XCD-co-located);
// appended blocks run PV for the PREVIOUS chunk (TERMS=1, BKH=64, full-K,
// writes out directly). PV blocks fill the matrix-pipe slots the S-GEMM
// leaves idle (46% MfmaUtil alone; co-resident pipes co-schedule, m114).
__global__ __launch_bounds__(256, 4) void sgemm_pv(
    const _Float16* __restrict__ Qh, const _Float16* __restrict__ Ql,
    const _Float16* __restrict__ Kh, const _Float16* __restrict__ Kl,
    float* __restrict__ Sc, int gemmY,
    const _Float16* __restrict__ P, const _Float16* __restrict__ XT,
    float* __restrict__ Out, int pvNB) {
    __shared__ __align__(16) _Float16 s[16384];
    const long Nt = 8192, D = 1024;
    if ((int)blockIdx.y < gemmY) {
        gemm_core<3, 0, 32>(Qh, Ql, Kh, Kl, Sc, nullptr, nullptr,
                            D, D, Nt, (int)D,
                            (long)blockIdx.y * TM, (long)blockIdx.x * TN, s);
    } else {
        int idx = ((int)blockIdx.y - gemmY) * 64 + (int)blockIdx.x;
        if (idx >= pvNB) return;
        int rb = idx >> 3, cb = idx & 7;
        gemm_core<1, 0, 64>(P, nullptr, XT, nullptr, Out, nullptr, nullptr,
                            Nt, Nt, D, (int)Nt,
                            (long)rb * TM, (long)cb * TN, s);
    }
}

// ---------------------------------------------------------------- softmax
// One block per row (8192 fp32). Whole row into registers (paired float4),
// reduce max and sum(exp), write P f16 16B chunks (may alias the fp32 row
// in-place). Scale 1/32 folded in.
__global__ __launch_bounds__(256) void softmax_rows(const float* __restrict__ S,
                                                    _Float16* __restrict__ P,
                                                    long ldp, int N) {
    const int row = blockIdx.x;
    const int t = threadIdx.x;
    const float4* rowp = (const float4*)(S + (size_t)row * N);
    float4 v[8];
    float mx = -3.4e38f;
#pragma unroll
    for (int g = 0; g < 4; ++g) {
        v[2 * g]     = rowp[2 * t + 512 * g];
        v[2 * g + 1] = rowp[2 * t + 512 * g + 1];
    }
#pragma unroll
    for (int i = 0; i < 8; ++i)
        mx = fmaxf(mx, fmaxf(fmaxf(v[i].x, v[i].y), fmaxf(v[i].z, v[i].w)));
    __shared__ float red[8];
#pragma unroll
    for (int off = 32; off >= 1; off >>= 1) mx = fmaxf(mx, __shfl_xor(mx, off));
    if ((t & 63) == 0) red[t >> 6] = mx;
    __syncthreads();
    mx = fmaxf(fmaxf(red[0], red[1]), fmaxf(red[2], red[3]));

    float sum = 0.0f;
#pragma unroll
    for (int i = 0; i < 8; ++i) {
        v[i].x = __expf((v[i].x - mx) * 0.03125f);
        v[i].y = __expf((v[i].y - mx) * 0.03125f);
        v[i].z = __expf((v[i].z - mx) * 0.03125f);
        v[i].w = __expf((v[i].w - mx) * 0.03125f);
        sum += (v[i].x + v[i].y) + (v[i].z + v[i].w);
    }
#pragma unroll
    for (int off = 32; off >= 1; off >>= 1) sum += __shfl_xor(sum, off);
    if ((t & 63) == 0) red[4 + (t >> 6)] = sum;
    __syncthreads();
    float inv = 1.0f / (red[4] + red[5] + red[6] + red[7]);

    f16x8* prow = (f16x8*)(P + (size_t)row * ldp);
#pragma unroll
    for (int g = 0; g < 4; ++g) {
        float4 a = v[2 * g], b = v[2 * g + 1];
        f16x8 o;
        o[0] = (_Float16)(a.x * inv); o[1] = (_Float16)(a.y * inv);
        o[2] = (_Float16)(a.z * inv); o[3] = (_Float16)(a.w * inv);
        o[4] = (_Float16)(b.x * inv); o[5] = (_Float16)(b.y * inv);
        o[6] = (_Float16)(b.z * inv); o[7] = (_Float16)(b.w * inv);
        prow[t + 256 * g] = o;
    }
}

// ---------------------------------------------------------------- launch
extern "C" void kernel_launch(void* const* d_in, const int* in_sizes, int n_in,
                              void* d_out, int out_size, void* d_ws, size_t ws_size,
                              hipStream_t stream) {
    const float* X  = (const float*)d_in[0];  // [8192,1024]
    const float* Wq = (const float*)d_in[1];  // [1024,1024]
    const float* Wk = (const float*)d_in[2];  // [1024,1024]
    float* out = (float*)d_out;               // [8192,1024]

    const long Nt = 8192, D = 1024;
    char* ws = (char*)d_ws;
    const size_t MB = 1024ull * 1024ull;

    // Persistent region (80 MB):
    _Float16* XT  = (_Float16*)(ws + 0);        // 16 MB [1024][8192] = X^T f16
    _Float16* Qhi = (_Float16*)(ws + 16 * MB);  // 16 MB each
    _Float16* Qlo = (_Float16*)(ws + 32 * MB);
    _Float16* Khi = (_Float16*)(ws + 48 * MB);
    _Float16* Klo = (_Float16*)(ws + 64 * MB);
    // Transient (dead after projections):
    _Float16* Xhi   = (_Float16*)(ws + 80 * MB);   // 16 MB
    _Float16* Xlo   = (_Float16*)(ws + 96 * MB);   // 16 MB
    _Float16* WqThi = (_Float16*)(ws + 112 * MB);  // 2 MB each, Wq/Wk adjacent
    _Float16* WqTlo = (_Float16*)(ws + 114 * MB);

    const size_t rowBytes = (size_t)Nt * 4;  // 32 KB per S row
    const bool planA = ws_size >= 208 * MB + 128 * rowBytes;
    _Float16* Pbuf = (_Float16*)(ws + 80 * MB);   // plan A: 128 MB compact P

    // 1. prep: one pass over X -> Xhi,Xlo,XT; both weight transposes fused
    prep_x<<<dim3(32, 256), dim3(32, 8), 0, stream>>>(X, Xhi, Xlo, XT,
                                                      (int)Nt, (int)D);
    transpose_split2<<<dim3(32, 32, 2), dim3(32, 8), 0, stream>>>(
        Wq, Wk, WqThi, WqTlo, (int)D, (int)D, (long)(4 * MB / 2));

    // 2. fused Q+K projections (3-term split), z=0 -> Q, z=1 -> K.
    //    zB = WkThi-WqThi = 4 MB = 2M halves; zC = Khi-Qhi = 16M halves.
    //    1024 blocks at 4/CU -> fully resident.
    gemm_bt<3, 1, 1, 32><<<dim3(Nt / TM, D / TN, 2), 256, 0, stream>>>(
        Xhi, Xlo, WqThi, WqTlo, nullptr, Qhi, Qlo, D, D, D, (int)D,
        0, (long)(4 * MB / 2), (long)(32 * MB / 2));

    if (planA) {
        float* Sc = (float*)(ws + 208 * MB);
        size_t avail = ws_size - 208 * MB;
        long chunk = (long)((avail / rowBytes / 128) * 128);
        if (chunk > Nt) chunk = Nt;
        long nch = (Nt + chunk - 1) / chunk;
        chunk = (((Nt + nch - 1) / nch) + 127) / 128 * 128;

        // 3. chunk pipeline:
        //    SG(0) | SM(0) | SG(1)+PV(0) | SM(1) | ... | SM(last) | PV(last)
        //    PV(c) = P-rows of chunk c @ X (full-K, out rows written once).
        long done = 0, prevDone = 0, prevCur = 0;
        int c = 0;
        while (done < Nt) {
            long cur = Nt - done < chunk ? Nt - done : chunk;
            int gemmY = (int)(cur / TM);
            int pvNB = (c >= 1) ? (int)(prevCur / TM) * 8 : 0;
            int pvY = (pvNB + 63) / 64;
            sgemm_pv<<<dim3(Nt / TN, gemmY + pvY), 256, 0, stream>>>(
                Qhi + done * D, Qlo + done * D, Khi, Klo, Sc, gemmY,
                Pbuf + prevDone * Nt, XT, out + prevDone * D, pvNB);
            softmax_rows<<<(int)cur, 256, 0, stream>>>(
                Sc, Pbuf + done * Nt, Nt, (int)Nt);
            prevDone = done; prevCur = cur;
            done += cur; ++c;
        }
        // final chunk's PV (no S-GEMM partner left)
        {
            int pvNB = (int)(prevCur / TM) * 8;
            int pvY = (pvNB + 63) / 64;
            sgemm_pv<<<dim3(Nt / TN, pvY), 256, 0, stream>>>(
                Qhi, Qlo, Khi, Klo, Sc, 0,
                Pbuf + prevDone * Nt, XT, out + prevDone * D, pvNB);
        }
    } else {
        // Plan B (small ws): serial chunks, in-place P, per-chunk PV.
        float* Sc = (float*)(ws + 80 * MB);
        size_t avail = ws_size > 80 * MB ? ws_size - 80 * MB : 0;
        long chunk = (long)((avail / rowBytes / 128) * 128);
        if (chunk < 128) chunk = 128;
        if (chunk > Nt) chunk = Nt;
        long nch = (Nt + chunk - 1) / chunk;
        chunk = (((Nt + nch - 1) / nch) + 127) / 128 * 128;
        long done = 0;
        while (done < Nt) {
            long cur = Nt - done < chunk ? Nt - done : chunk;
            gemm_bt<3, 0, 0, 32>
                <<<dim3(Nt / TN, cur / TM, 1), 256, 0, stream>>>(
                Qhi + done * D, Qlo + done * D, Khi, Klo, Sc, nullptr, nullptr,
                D, D, Nt, (int)D, 0, 0, 0);
            softmax_rows<<<(int)cur, 256, 0, stream>>>(Sc, (_Float16*)Sc,
                                                       2 * Nt, (int)Nt);
            gemm_bt<1, 0, 1, 64>
                <<<dim3(cur / TM, D / TN, 1), 256, 0, stream>>>(
                (const _Float16*)Sc, nullptr, XT, nullptr,
                out + done * D, nullptr, nullptr, 2 * Nt, Nt, D, (int)Nt,
                0, 0, 0);
            done += cur;
        }
    }
}

// Round 11
// 879.132 us; speedup vs baseline: 1.4163x; 1.4163x over previous
//
#include <hip/hip_runtime.h>
#include <hip/hip_bf16.h>

// Self-attention: context = softmax((X@Wq)(X@Wk)^T / sqrt(d)) @ X
// N=8192, d=1024, fp32. Near-one-hot scores => fp32-grade score accuracy:
// f16 split (hi+lo, 3-term Ootomo) MFMA GEMMs for projections and QK^T;
// plain f16 MFMA for P@V.
//
// R11: revert R10's fused PV (88 full-K blocks -> 90us 1-block/CU tail,
//      Occupancy 13%, 1245us total). Back to R8 (814us best) plus:
//      (a) PV split-K=2 accumulates via fp32 atomicAdd into out (2-way
//          fp32 add is order-independent -> deterministic); add_rows and
//          PK buffers eliminated (~25us, 160 MB traffic);
//      (b) both weight transposes in one launch.
//      R8 invariants kept: 16x16 MFMA + XOR swizzle (0 LDS conflicts),
//      4 blocks/CU, SG SWAP=0, PV SWAP=1.

typedef _Float16 f16x8 __attribute__((ext_vector_type(8)));
typedef float    f32x4 __attribute__((ext_vector_type(4)));

#define TM 128
#define TN 128

// async global->LDS, 16 B per lane; LDS dest = wave-uniform base + lane*16
__device__ __forceinline__ void g2lds16(const _Float16* g, _Float16* l) {
    __builtin_amdgcn_global_load_lds(
        (__attribute__((address_space(1))) unsigned int*)(g),
        (__attribute__((address_space(3))) unsigned int*)(l),
        16, 0, 0);
}

// ---------------------------------------------------------------- helpers

// one pass over X: write Xhi/Xlo (row-major split) and XT (f16 transpose)
__global__ void prep_x(const float* __restrict__ src,
                       _Float16* __restrict__ hi, _Float16* __restrict__ lo,
                       _Float16* __restrict__ xt, int R, int C) {
    __shared__ float tile[32][33];
    int c0 = blockIdx.x * 32, r0 = blockIdx.y * 32;
    int tx = threadIdx.x, ty = threadIdx.y;   // (32, 8)
#pragma unroll
    for (int k = 0; k < 4; ++k) {
        int r = ty + 8 * k;
        size_t idx = (size_t)(r0 + r) * C + c0 + tx;
        float v = src[idx];
        tile[r][tx] = v;
        _Float16 h = (_Float16)v;
        hi[idx] = h;
        lo[idx] = (_Float16)(v - (float)h);
    }
    __syncthreads();
#pragma unroll
    for (int k = 0; k < 4; ++k) {
        float v = tile[tx][ty + 8 * k];
        xt[(size_t)(c0 + ty + 8 * k) * R + r0 + tx] = (_Float16)v;
    }
}

// dst[c][r] = src[r][c] with f16 hi/lo split; z selects (Wq,Wk) source and
// shifts the dst by zOff elements (hi and lo shift together).
__global__ void transpose_split2(const float* __restrict__ srcQ,
                                 const float* __restrict__ srcK,
                                 _Float16* __restrict__ dhi,
                                 _Float16* __restrict__ dlo,
                                 int R, int C, long zOff) {
    __shared__ float tile[32][33];
    const float* src = blockIdx.z ? srcK : srcQ;
    _Float16* hi = dhi + blockIdx.z * zOff;
    _Float16* lo = dlo + blockIdx.z * zOff;
    int c0 = blockIdx.x * 32, r0 = blockIdx.y * 32;
    int tx = threadIdx.x, ty = threadIdx.y;   // (32, 8)
#pragma unroll
    for (int k = 0; k < 4; ++k)
        tile[ty + 8 * k][tx] = src[(size_t)(r0 + ty + 8 * k) * C + c0 + tx];
    __syncthreads();
#pragma unroll
    for (int k = 0; k < 4; ++k) {
        float v = tile[tx][ty + 8 * k];
        _Float16 h = (_Float16)v;
        size_t idx = (size_t)(c0 + ty + 8 * k) * R + r0 + tx;
        hi[idx] = h;
        lo[idx] = (_Float16)(v - (float)h);
    }
}

// ---------------------------------------------------------------- GEMM
// C[M,N] fp32 = sum_k A[M,K] * B_bt[N,K]^T (row-major; B transposed form).
// TERMS==3: A = Ahi+Alo, B = Bhi+Blo, compute hh + hl + lh (Ootomo 3-term).
// SPLIT_OUT==1: epilogue stores f16 hi/lo pair instead of fp32.
// SWAP==1: blockIdx.x indexes row-blocks (A-reuse XCD-co-located).
// BKH: k-step in halves (32 or 64); LDS rows XOR-swizzled (0-conflict,
// measured R6/R8). ATOMIC==1: epilogue atomicAdd into C (split-K reduce;
// 2-way fp32 add is order-independent -> deterministic).
// gridDim.z slices via element offsets zA/zB/zC (fused proj / split-K PV).
template <int TERMS, int SPLIT_OUT, int SWAP, int BKH, int ATOMIC>
__global__ __launch_bounds__(256, 4) void gemm_bt(
    const _Float16* __restrict__ Ahi, const _Float16* __restrict__ Alo,
    const _Float16* __restrict__ Bhi, const _Float16* __restrict__ Blo,
    float* __restrict__ C, _Float16* __restrict__ Chi, _Float16* __restrict__ Clo,
    long lda, long ldb, long ldc, int K, long zA, long zB, long zC) {
    constexpr int NBUF = (TERMS == 3) ? 4 : 2;     // hi/lo x A/B  or  A/B
    __shared__ __align__(16) _Float16 s[NBUF * 128 * BKH];

    const long z = blockIdx.z;
    Ahi += z * zA;
    Bhi += z * zB;
    if constexpr (TERMS == 3) { Alo += z * zA; Blo += z * zB; }
    if constexpr (SPLIT_OUT) { Chi += z * zC; Clo += z * zC; }
    else C += z * zC;

    const int t = threadIdx.x;
    const int wave = t >> 6;
    const int lane = t & 63;
    const int lm = lane & 15;     // row/col within 16-tile
    const int lq = lane >> 4;     // quad 0..3
    const int wr = wave >> 1;     // wave row 0..1
    const int wc = wave & 1;      // wave col 0..1

    const long rowBase = (long)(SWAP ? blockIdx.x : blockIdx.y) * TM;
    const long colBase = (long)(SWAP ? blockIdx.y : blockIdx.x) * TN;

    // --- staging assignment (per wave) ---
    const _Float16* src;
    long myLd, gRow0;
    int ldsBaseH;
    if constexpr (TERMS == 3) {
        // wave 0: Ahi  1: Alo  2: Bhi  3: Blo ; 128 rows each
        const _Float16* a = (wave & 1) ? Alo : Ahi;
        const _Float16* b = (wave & 1) ? Blo : Bhi;
        src = (wave & 2) ? b : a;
        myLd = (wave & 2) ? ldb : lda;
        gRow0 = (wave & 2) ? colBase : rowBase;
        ldsBaseH = wave * (128 * BKH);
    } else {
        // wave 0: A rows 0-63  1: A rows 64-127  2: B 0-63  3: B 64-127
        src = (wave & 2) ? Bhi : Ahi;
        myLd = (wave & 2) ? ldb : lda;
        gRow0 = ((wave & 2) ? colBase : rowBase) + (wave & 1) * 64;
        ldsBaseH = (wave >> 1) * (128 * BKH) + (wave & 1) * (64 * BKH);
    }
    constexpr int LPR = BKH / 8;          // lanes per row: 4 or 8
    constexpr int RPI = 64 / LPR;         // rows per 1KB issue: 16 or 8
    constexpr int NISS = (TERMS == 3 ? 128 : 64) / RPI;   // 8 both ways
    const int lr = lane / LPR;            // row within issue
    const int slot = lane % LPR;          // 16B column slot
    // XOR swizzle: LDS[row][slot] holds global col group slot^swz(row);
    // issues stride RPI rows -> swz is lane-invariant across issues.
    const int swzW = (BKH == 32) ? ((lr >> 1) & 3) : (lr & 7);
    const _Float16* rp = src + (gRow0 + lr) * myLd + (slot ^ swzW) * 8;
    _Float16* ldsW = &s[ldsBaseH];

    const _Float16* sAh = s;
    const _Float16* sBh = s + (TERMS == 3 ? 2 : 1) * 128 * BKH;
    const _Float16* sAl = s + 128 * BKH;       // TERMS==3 only
    const _Float16* sBl = s + 3 * 128 * BKH;   // TERMS==3 only

    const int swzR = (BKH == 32) ? ((lm >> 1) & 3) : (lm & 7);

    f32x4 acc[4][4];
#pragma unroll
    for (int r = 0; r < 4; ++r)
#pragma unroll
        for (int c = 0; c < 4; ++c)
#pragma unroll
            for (int i = 0; i < 4; ++i) acc[r][c][i] = 0.0f;

    for (int k0 = 0; k0 < K; k0 += BKH) {
        __syncthreads();   // LDS safe to overwrite
#pragma unroll
        for (int j = 0; j < NISS; ++j)
            g2lds16(rp + (long)(j * RPI) * myLd + k0, ldsW + j * 512);
        __syncthreads();   // drains vmcnt before barrier => data visible

#pragma unroll
        for (int kk = 0; kk < BKH; kk += 32) {
            const int gb = kk >> 3;   // column-group base (8 halves/group)
            f16x8 ah[4], bh[4], al[4], bl[4];
#pragma unroll
            for (int r = 0; r < 4; ++r) {
                int ra = (wr * 64 + r * 16 + lm) * BKH + ((gb + lq) ^ swzR) * 8;
                int rb = (wc * 64 + r * 16 + lm) * BKH + ((gb + lq) ^ swzR) * 8;
                ah[r] = *(const f16x8*)&sAh[ra];
                bh[r] = *(const f16x8*)&sBh[rb];
                if constexpr (TERMS == 3) {
                    al[r] = *(const f16x8*)&sAl[ra];
                    bl[r] = *(const f16x8*)&sBl[rb];
                }
            }
#pragma unroll
            for (int r = 0; r < 4; ++r)
#pragma unroll
                for (int c = 0; c < 4; ++c) {
                    acc[r][c] = __builtin_amdgcn_mfma_f32_16x16x32_f16(
                        ah[r], bh[c], acc[r][c], 0, 0, 0);
                    if constexpr (TERMS == 3) {
                        acc[r][c] = __builtin_amdgcn_mfma_f32_16x16x32_f16(
                            ah[r], bl[c], acc[r][c], 0, 0, 0);
                        acc[r][c] = __builtin_amdgcn_mfma_f32_16x16x32_f16(
                            al[r], bh[c], acc[r][c], 0, 0, 0);
                    }
                }
        }
    }

    // C/D layout: col = lane&15, row = quad*4 + reg  (verified m89/m91)
#pragma unroll
    for (int r = 0; r < 4; ++r)
#pragma unroll
        for (int c = 0; c < 4; ++c)
#pragma unroll
            for (int i = 0; i < 4; ++i) {
                long row = rowBase + wr * 64 + r * 16 + lq * 4 + i;
                long col = colBase + wc * 64 + c * 16 + lm;
                if constexpr (SPLIT_OUT) {
                    float v = acc[r][c][i];
                    _Float16 h = (_Float16)v;
                    Chi[row * ldc + col] = h;
                    Clo[row * ldc + col] = (_Float16)(v - (float)h);
                } else if constexpr (ATOMIC) {
                    atomicAdd(&C[row * ldc + col], acc[r][c][i]);
                } else {
                    C[row * ldc + col] = acc[r][c][i];
                }
            }
}

// ---------------------------------------------------------------- softmax
// One block per row (8192 fp32). Whole row into registers (paired float4 =
// 32 B/lane contiguous), reduce max and sum(exp), write P f16 as 16 B
// chunks (may alias the fp32 row in-place). Scale 1/32 folded in.
__global__ __launch_bounds__(256) void softmax_rows(const float* __restrict__ S,
                                                    _Float16* __restrict__ P,
                                                    long ldp, int N) {
    const int row = blockIdx.x;
    const int t = threadIdx.x;
    const float4* rowp = (const float4*)(S + (size_t)row * N);
    float4 v[8];
    float mx = -3.4e38f;
#pragma unroll
    for (int g = 0; g < 4; ++g) {
        v[2 * g]     = rowp[2 * t + 512 * g];
        v[2 * g + 1] = rowp[2 * t + 512 * g + 1];
    }
#pragma unroll
    for (int i = 0; i < 8; ++i)
        mx = fmaxf(mx, fmaxf(fmaxf(v[i].x, v[i].y), fmaxf(v[i].z, v[i].w)));
    __shared__ float red[8];
#pragma unroll
    for (int off = 32; off >= 1; off >>= 1) mx = fmaxf(mx, __shfl_xor(mx, off));
    if ((t & 63) == 0) red[t >> 6] = mx;
    __syncthreads();
    mx = fmaxf(fmaxf(red[0], red[1]), fmaxf(red[2], red[3]));

    float sum = 0.0f;
#pragma unroll
    for (int i = 0; i < 8; ++i) {
        v[i].x = __expf((v[i].x - mx) * 0.03125f);
        v[i].y = __expf((v[i].y - mx) * 0.03125f);
        v[i].z = __expf((v[i].z - mx) * 0.03125f);
        v[i].w = __expf((v[i].w - mx) * 0.03125f);
        sum += (v[i].x + v[i].y) + (v[i].z + v[i].w);
    }
#pragma unroll
    for (int off = 32; off >= 1; off >>= 1) sum += __shfl_xor(sum, off);
    if ((t & 63) == 0) red[4 + (t >> 6)] = sum;
    __syncthreads();
    float inv = 1.0f / (red[4] + red[5] + red[6] + red[7]);

    f16x8* prow = (f16x8*)(P + (size_t)row * ldp);
#pragma unroll
    for (int g = 0; g < 4; ++g) {
        float4 a = v[2 * g], b = v[2 * g + 1];
        f16x8 o;
        o[0] = (_Float16)(a.x * inv); o[1] = (_Float16)(a.y * inv);
        o[2] = (_Float16)(a.z * inv); o[3] = (_Float16)(a.w * inv);
        o[4] = (_Float16)(b.x * inv); o[5] = (_Float16)(b.y * inv);
        o[6] = (_Float16)(b.z * inv); o[7] = (_Float16)(b.w * inv);
        prow[t + 256 * g] = o;
    }
}

// ---------------------------------------------------------------- launch
extern "C" void kernel_launch(void* const* d_in, const int* in_sizes, int n_in,
                              void* d_out, int out_size, void* d_ws, size_t ws_size,
                              hipStream_t stream) {
    const float* X  = (const float*)d_in[0];  // [8192,1024]
    const float* Wq = (const float*)d_in[1];  // [1024,1024]
    const float* Wk = (const float*)d_in[2];  // [1024,1024]
    float* out = (float*)d_out;               // [8192,1024]

    const long Nt = 8192, D = 1024;
    char* ws = (char*)d_ws;
    const size_t MB = 1024ull * 1024ull;

    // Persistent region (80 MB):
    _Float16* XT  = (_Float16*)(ws + 0);        // 16 MB [1024][8192] = X^T f16
    _Float16* Qhi = (_Float16*)(ws + 16 * MB);  // 16 MB each
    _Float16* Qlo = (_Float16*)(ws + 32 * MB);
    _Float16* Khi = (_Float16*)(ws + 48 * MB);
    _Float16* Klo = (_Float16*)(ws + 64 * MB);
    // Transient (dead after projections):
    _Float16* Xhi   = (_Float16*)(ws + 80 * MB);   // 16 MB
    _Float16* Xlo   = (_Float16*)(ws + 96 * MB);   // 16 MB
    _Float16* WqThi = (_Float16*)(ws + 112 * MB);  // 2 MB each, Wq/Wk adjacent
    _Float16* WqTlo = (_Float16*)(ws + 114 * MB);

    const size_t rowBytes = (size_t)Nt * 4;  // 32 KB per S row
    const bool planA = ws_size >= 208 * MB + 128 * rowBytes;
    _Float16* Pbuf = (_Float16*)(ws + 80 * MB);   // plan A: 128 MB compact P

    // 1. prep: one pass over X -> Xhi,Xlo,XT; both weight transposes fused
    prep_x<<<dim3(32, 256), dim3(32, 8), 0, stream>>>(X, Xhi, Xlo, XT,
                                                      (int)Nt, (int)D);
    transpose_split2<<<dim3(32, 32, 2), dim3(32, 8), 0, stream>>>(
        Wq, Wk, WqThi, WqTlo, (int)D, (int)D, (long)(4 * MB / 2));

    // 2. fused Q+K projections (3-term split), z=0 -> Q, z=1 -> K.
    //    zB = WkThi-WqThi = 4 MB = 2M halves; zC = Khi-Qhi = 16M halves.
    //    1024 blocks at 4/CU -> fully resident.
    gemm_bt<3, 1, 1, 32, 0><<<dim3(Nt / TM, D / TN, 2), 256, 0, stream>>>(
        Xhi, Xlo, WqThi, WqTlo, nullptr, Qhi, Qlo, D, D, D, (int)D,
        0, (long)(4 * MB / 2), (long)(32 * MB / 2));

    if (planA) {
        float* Sc = (float*)(ws + 208 * MB);
        size_t avail = ws_size - 208 * MB;
        long chunk = (long)((avail / rowBytes / 128) * 128);
        if (chunk > Nt) chunk = Nt;
        long nch = (Nt + chunk - 1) / chunk;
        chunk = (((Nt + nch - 1) / nch) + 127) / 128 * 128;

        // 3. serial chunks: S = Q@K^T (SWAP=0: 64 col-blocks = K-splits
        //    XCD-co-located), then softmax -> compact P f16.
        long done = 0;
        while (done < Nt) {
            long cur = Nt - done < chunk ? Nt - done : chunk;
            gemm_bt<3, 0, 0, 32, 0>
                <<<dim3(Nt / TN, cur / TM, 1), 256, 0, stream>>>(
                Qhi + done * D, Qlo + done * D, Khi, Klo, Sc, nullptr, nullptr,
                D, D, Nt, (int)D, 0, 0, 0);
            softmax_rows<<<(int)cur, 256, 0, stream>>>(
                Sc, Pbuf + done * Nt, Nt, (int)Nt);
            done += cur;
        }

        // 4. PV split-K=2, BK=64, SWAP=1 (measured best: grid (64,8,2) ->
        //    id%8 = row-block%8, P row-tile co-located per XCD; 0 LDS
        //    conflicts). z slices K; both z atomically accumulate into out
        //    (zeroed first) -- add_rows + PK round-trip eliminated.
        hipMemsetAsync(out, 0, (size_t)Nt * D * 4, stream);
        gemm_bt<1, 0, 1, 64, 1><<<dim3(Nt / TM, D / TN, 2), 256, 0, stream>>>(
            Pbuf, nullptr, XT, nullptr, out, nullptr, nullptr,
            Nt, Nt, D, (int)(Nt / 2),
            Nt / 2, Nt / 2, 0);
    } else {
        // Plan B (small ws): serial chunks, in-place P, per-chunk PV.
        float* Sc = (float*)(ws + 80 * MB);
        size_t avail = ws_size > 80 * MB ? ws_size - 80 * MB : 0;
        long chunk = (long)((avail / rowBytes / 128) * 128);
        if (chunk < 128) chunk = 128;
        if (chunk > Nt) chunk = Nt;
        long nch = (Nt + chunk - 1) / chunk;
        chunk = (((Nt + nch - 1) / nch) + 127) / 128 * 128;
        long done = 0;
        while (done < Nt) {
            long cur = Nt - done < chunk ? Nt - done : chunk;
            gemm_bt<3, 0, 0, 32, 0>
                <<<dim3(Nt / TN, cur / TM, 1), 256, 0, stream>>>(
                Qhi + done * D, Qlo + done * D, Khi, Klo, Sc, nullptr, nullptr,
                D, D, Nt, (int)D, 0, 0, 0);
            softmax_rows<<<(int)cur, 256, 0, stream>>>(Sc, (_Float16*)Sc,
                                                       2 * Nt, (int)Nt);
            gemm_bt<1, 0, 1, 64, 0>
                <<<dim3(cur / TM, D / TN, 1), 256, 0, stream>>>(
                (const _Float16*)Sc, nullptr, XT, nullptr,
                out + done * D, nullptr, nullptr, 2 * Nt, Nt, D, (int)Nt,
                0, 0, 0);
            done += cur;
        }
    }
}

// Round 12
// 815.912 us; speedup vs baseline: 1.5261x; 1.0775x over previous
//
#include <hip/hip_runtime.h>
#include <hip/hip_bf16.h>

// Self-attention: context = softmax((X@Wq)(X@Wk)^T / sqrt(d)) @ X
// N=8192, d=1024, fp32. Near-one-hot scores => fp32-grade score accuracy:
// f16 split (hi+lo, 3-term Ootomo) MFMA GEMMs for projections and QK^T;
// plain f16 MFMA for P@V.
//
// R12: revert R11's atomic split-K (PV 114->177us: 16.8M global atomics
//      throttle in L2; add_rows is cheaper). Exact R8 structure (best,
//      814us) + merged weight transposes. Verified invariants:
//      - 16x16 MFMA + XOR-swizzled LDS = 0 bank conflicts (R6/R8)
//      - 4 blocks/CU (launch_bounds 256,4); SG SWAP=0; PV SWAP=1 splitK=2
//      - PK partials + add_rows for the reduce (atomics measured -63us)
//      - overlap fusions all measured worse (R9 -65, R10 -430, R11 -65)

typedef _Float16 f16x8 __attribute__((ext_vector_type(8)));
typedef float    f32x4 __attribute__((ext_vector_type(4)));

#define TM 128
#define TN 128

// async global->LDS, 16 B per lane; LDS dest = wave-uniform base + lane*16
__device__ __forceinline__ void g2lds16(const _Float16* g, _Float16* l) {
    __builtin_amdgcn_global_load_lds(
        (__attribute__((address_space(1))) unsigned int*)(g),
        (__attribute__((address_space(3))) unsigned int*)(l),
        16, 0, 0);
}

// ---------------------------------------------------------------- helpers

// one pass over X: write Xhi/Xlo (row-major split) and XT (f16 transpose)
__global__ void prep_x(const float* __restrict__ src,
                       _Float16* __restrict__ hi, _Float16* __restrict__ lo,
                       _Float16* __restrict__ xt, int R, int C) {
    __shared__ float tile[32][33];
    int c0 = blockIdx.x * 32, r0 = blockIdx.y * 32;
    int tx = threadIdx.x, ty = threadIdx.y;   // (32, 8)
#pragma unroll
    for (int k = 0; k < 4; ++k) {
        int r = ty + 8 * k;
        size_t idx = (size_t)(r0 + r) * C + c0 + tx;
        float v = src[idx];
        tile[r][tx] = v;
        _Float16 h = (_Float16)v;
        hi[idx] = h;
        lo[idx] = (_Float16)(v - (float)h);
    }
    __syncthreads();
#pragma unroll
    for (int k = 0; k < 4; ++k) {
        float v = tile[tx][ty + 8 * k];
        xt[(size_t)(c0 + ty + 8 * k) * R + r0 + tx] = (_Float16)v;
    }
}

// dst[c][r] = src[r][c] with f16 hi/lo split; z selects (Wq,Wk) source and
// shifts the dst by zOff elements (hi and lo shift together).
__global__ void transpose_split2(const float* __restrict__ srcQ,
                                 const float* __restrict__ srcK,
                                 _Float16* __restrict__ dhi,
                                 _Float16* __restrict__ dlo,
                                 int R, int C, long zOff) {
    __shared__ float tile[32][33];
    const float* src = blockIdx.z ? srcK : srcQ;
    _Float16* hi = dhi + blockIdx.z * zOff;
    _Float16* lo = dlo + blockIdx.z * zOff;
    int c0 = blockIdx.x * 32, r0 = blockIdx.y * 32;
    int tx = threadIdx.x, ty = threadIdx.y;   // (32, 8)
#pragma unroll
    for (int k = 0; k < 4; ++k)
        tile[ty + 8 * k][tx] = src[(size_t)(r0 + ty + 8 * k) * C + c0 + tx];
    __syncthreads();
#pragma unroll
    for (int k = 0; k < 4; ++k) {
        float v = tile[tx][ty + 8 * k];
        _Float16 h = (_Float16)v;
        size_t idx = (size_t)(c0 + ty + 8 * k) * R + r0 + tx;
        hi[idx] = h;
        lo[idx] = (_Float16)(v - (float)h);
    }
}

// out = a + b (final split-K reduction), float4 grid-stride
__global__ __launch_bounds__(256) void add_rows(const float* __restrict__ a,
                                                const float* __restrict__ b,
                                                float* __restrict__ out, long n4) {
    long i = (long)blockIdx.x * blockDim.x + threadIdx.x;
    long stride = (long)gridDim.x * blockDim.x;
    for (; i < n4; i += stride) {
        float4 x = ((const float4*)a)[i];
        float4 y = ((const float4*)b)[i];
        x.x += y.x; x.y += y.y; x.z += y.z; x.w += y.w;
        ((float4*)out)[i] = x;
    }
}

// ---------------------------------------------------------------- GEMM
// C[M,N] fp32 = sum_k A[M,K] * B_bt[N,K]^T (row-major; B transposed form).
// TERMS==3: A = Ahi+Alo, B = Bhi+Blo, compute hh + hl + lh (Ootomo 3-term).
// SPLIT_OUT==1: epilogue stores f16 hi/lo pair instead of fp32.
// SWAP==1: blockIdx.x indexes row-blocks (A-reuse XCD-co-located).
// BKH: k-step in halves (32 or 64); LDS rows XOR-swizzled (0-conflict,
// measured R6/R8). gridDim.z slices via element offsets zA/zB/zC.
template <int TERMS, int SPLIT_OUT, int SWAP, int BKH>
__global__ __launch_bounds__(256, 4) void gemm_bt(
    const _Float16* __restrict__ Ahi, const _Float16* __restrict__ Alo,
    const _Float16* __restrict__ Bhi, const _Float16* __restrict__ Blo,
    float* __restrict__ C, _Float16* __restrict__ Chi, _Float16* __restrict__ Clo,
    long lda, long ldb, long ldc, int K, long zA, long zB, long zC) {
    constexpr int NBUF = (TERMS == 3) ? 4 : 2;     // hi/lo x A/B  or  A/B
    __shared__ __align__(16) _Float16 s[NBUF * 128 * BKH];

    const long z = blockIdx.z;
    Ahi += z * zA;
    Bhi += z * zB;
    if constexpr (TERMS == 3) { Alo += z * zA; Blo += z * zB; }
    if constexpr (SPLIT_OUT) { Chi += z * zC; Clo += z * zC; }
    else C += z * zC;

    const int t = threadIdx.x;
    const int wave = t >> 6;
    const int lane = t & 63;
    const int lm = lane & 15;     // row/col within 16-tile
    const int lq = lane >> 4;     // quad 0..3
    const int wr = wave >> 1;     // wave row 0..1
    const int wc = wave & 1;      // wave col 0..1

    const long rowBase = (long)(SWAP ? blockIdx.x : blockIdx.y) * TM;
    const long colBase = (long)(SWAP ? blockIdx.y : blockIdx.x) * TN;

    // --- staging assignment (per wave) ---
    const _Float16* src;
    long myLd, gRow0;
    int ldsBaseH;
    if constexpr (TERMS == 3) {
        // wave 0: Ahi  1: Alo  2: Bhi  3: Blo ; 128 rows each
        const _Float16* a = (wave & 1) ? Alo : Ahi;
        const _Float16* b = (wave & 1) ? Blo : Bhi;
        src = (wave & 2) ? b : a;
        myLd = (wave & 2) ? ldb : lda;
        gRow0 = (wave & 2) ? colBase : rowBase;
        ldsBaseH = wave * (128 * BKH);
    } else {
        // wave 0: A rows 0-63  1: A rows 64-127  2: B 0-63  3: B 64-127
        src = (wave & 2) ? Bhi : Ahi;
        myLd = (wave & 2) ? ldb : lda;
        gRow0 = ((wave & 2) ? colBase : rowBase) + (wave & 1) * 64;
        ldsBaseH = (wave >> 1) * (128 * BKH) + (wave & 1) * (64 * BKH);
    }
    constexpr int LPR = BKH / 8;          // lanes per row: 4 or 8
    constexpr int RPI = 64 / LPR;         // rows per 1KB issue: 16 or 8
    constexpr int NISS = (TERMS == 3 ? 128 : 64) / RPI;   // 8 both ways
    const int lr = lane / LPR;            // row within issue
    const int slot = lane % LPR;          // 16B column slot
    // XOR swizzle: LDS[row][slot] holds global col group slot^swz(row);
    // issues stride RPI rows -> swz is lane-invariant across issues.
    const int swzW = (BKH == 32) ? ((lr >> 1) & 3) : (lr & 7);
    const _Float16* rp = src + (gRow0 + lr) * myLd + (slot ^ swzW) * 8;
    _Float16* ldsW = &s[ldsBaseH];

    const _Float16* sAh = s;
    const _Float16* sBh = s + (TERMS == 3 ? 2 : 1) * 128 * BKH;
    const _Float16* sAl = s + 128 * BKH;       // TERMS==3 only
    const _Float16* sBl = s + 3 * 128 * BKH;   // TERMS==3 only

    const int swzR = (BKH == 32) ? ((lm >> 1) & 3) : (lm & 7);

    f32x4 acc[4][4];
#pragma unroll
    for (int r = 0; r < 4; ++r)
#pragma unroll
        for (int c = 0; c < 4; ++c)
#pragma unroll
            for (int i = 0; i < 4; ++i) acc[r][c][i] = 0.0f;

    for (int k0 = 0; k0 < K; k0 += BKH) {
        __syncthreads();   // LDS safe to overwrite
#pragma unroll
        for (int j = 0; j < NISS; ++j)
            g2lds16(rp + (long)(j * RPI) * myLd + k0, ldsW + j * 512);
        __syncthreads();   // drains vmcnt before barrier => data visible

#pragma unroll
        for (int kk = 0; kk < BKH; kk += 32) {
            const int gb = kk >> 3;   // column-group base (8 halves/group)
            f16x8 ah[4], bh[4], al[4], bl[4];
#pragma unroll
            for (int r = 0; r < 4; ++r) {
                int ra = (wr * 64 + r * 16 + lm) * BKH + ((gb + lq) ^ swzR) * 8;
                int rb = (wc * 64 + r * 16 + lm) * BKH + ((gb + lq) ^ swzR) * 8;
                ah[r] = *(const f16x8*)&sAh[ra];
                bh[r] = *(const f16x8*)&sBh[rb];
                if constexpr (TERMS == 3) {
                    al[r] = *(const f16x8*)&sAl[ra];
                    bl[r] = *(const f16x8*)&sBl[rb];
                }
            }
#pragma unroll
            for (int r = 0; r < 4; ++r)
#pragma unroll
                for (int c = 0; c < 4; ++c) {
                    acc[r][c] = __builtin_amdgcn_mfma_f32_16x16x32_f16(
                        ah[r], bh[c], acc[r][c], 0, 0, 0);
                    if constexpr (TERMS == 3) {
                        acc[r][c] = __builtin_amdgcn_mfma_f32_16x16x32_f16(
                            ah[r], bl[c], acc[r][c], 0, 0, 0);
                        acc[r][c] = __builtin_amdgcn_mfma_f32_16x16x32_f16(
                            al[r], bh[c], acc[r][c], 0, 0, 0);
                    }
                }
        }
    }

    // C/D layout: col = lane&15, row = quad*4 + reg  (verified m89/m91)
#pragma unroll
    for (int r = 0; r < 4; ++r)
#pragma unroll
        for (int c = 0; c < 4; ++c)
#pragma unroll
            for (int i = 0; i < 4; ++i) {
                long row = rowBase + wr * 64 + r * 16 + lq * 4 + i;
                long col = colBase + wc * 64 + c * 16 + lm;
                if constexpr (SPLIT_OUT) {
                    float v = acc[r][c][i];
                    _Float16 h = (_Float16)v;
                    Chi[row * ldc + col] = h;
                    Clo[row * ldc + col] = (_Float16)(v - (float)h);
                } else {
                    C[row * ldc + col] = acc[r][c][i];
                }
            }
}

// ---------------------------------------------------------------- softmax
// One block per row (8192 fp32). Whole row into registers (paired float4 =
// 32 B/lane contiguous), reduce max and sum(exp), write P f16 as 16 B
// chunks (may alias the fp32 row in-place). Scale 1/32 folded in.
__global__ __launch_bounds__(256) void softmax_rows(const float* __restrict__ S,
                                                    _Float16* __restrict__ P,
                                                    long ldp, int N) {
    const int row = blockIdx.x;
    const int t = threadIdx.x;
    const float4* rowp = (const float4*)(S + (size_t)row * N);
    float4 v[8];
    float mx = -3.4e38f;
#pragma unroll
    for (int g = 0; g < 4; ++g) {
        v[2 * g]     = rowp[2 * t + 512 * g];
        v[2 * g + 1] = rowp[2 * t + 512 * g + 1];
    }
#pragma unroll
    for (int i = 0; i < 8; ++i)
        mx = fmaxf(mx, fmaxf(fmaxf(v[i].x, v[i].y), fmaxf(v[i].z, v[i].w)));
    __shared__ float red[8];
#pragma unroll
    for (int off = 32; off >= 1; off >>= 1) mx = fmaxf(mx, __shfl_xor(mx, off));
    if ((t & 63) == 0) red[t >> 6] = mx;
    __syncthreads();
    mx = fmaxf(fmaxf(red[0], red[1]), fmaxf(red[2], red[3]));

    float sum = 0.0f;
#pragma unroll
    for (int i = 0; i < 8; ++i) {
        v[i].x = __expf((v[i].x - mx) * 0.03125f);
        v[i].y = __expf((v[i].y - mx) * 0.03125f);
        v[i].z = __expf((v[i].z - mx) * 0.03125f);
        v[i].w = __expf((v[i].w - mx) * 0.03125f);
        sum += (v[i].x + v[i].y) + (v[i].z + v[i].w);
    }
#pragma unroll
    for (int off = 32; off >= 1; off >>= 1) sum += __shfl_xor(sum, off);
    if ((t & 63) == 0) red[4 + (t >> 6)] = sum;
    __syncthreads();
    float inv = 1.0f / (red[4] + red[5] + red[6] + red[7]);

    f16x8* prow = (f16x8*)(P + (size_t)row * ldp);
#pragma unroll
    for (int g = 0; g < 4; ++g) {
        float4 a = v[2 * g], b = v[2 * g + 1];
        f16x8 o;
        o[0] = (_Float16)(a.x * inv); o[1] = (_Float16)(a.y * inv);
        o[2] = (_Float16)(a.z * inv); o[3] = (_Float16)(a.w * inv);
        o[4] = (_Float16)(b.x * inv); o[5] = (_Float16)(b.y * inv);
        o[6] = (_Float16)(b.z * inv); o[7] = (_Float16)(b.w * inv);
        prow[t + 256 * g] = o;
    }
}

// ---------------------------------------------------------------- launch
extern "C" void kernel_launch(void* const* d_in, const int* in_sizes, int n_in,
                              void* d_out, int out_size, void* d_ws, size_t ws_size,
                              hipStream_t stream) {
    const float* X  = (const float*)d_in[0];  // [8192,1024]
    const float* Wq = (const float*)d_in[1];  // [1024,1024]
    const float* Wk = (const float*)d_in[2];  // [1024,1024]
    float* out = (float*)d_out;               // [8192,1024]

    const long Nt = 8192, D = 1024;
    char* ws = (char*)d_ws;
    const size_t MB = 1024ull * 1024ull;

    // Persistent region (80 MB):
    _Float16* XT  = (_Float16*)(ws + 0);        // 16 MB [1024][8192] = X^T f16
    _Float16* Qhi = (_Float16*)(ws + 16 * MB);  // 16 MB each  (dead after
    _Float16* Qlo = (_Float16*)(ws + 32 * MB);  //   S-GEMMs; reused as PK0/1)
    _Float16* Khi = (_Float16*)(ws + 48 * MB);
    _Float16* Klo = (_Float16*)(ws + 64 * MB);
    // Transient (dead after projections):
    _Float16* Xhi   = (_Float16*)(ws + 80 * MB);   // 16 MB
    _Float16* Xlo   = (_Float16*)(ws + 96 * MB);   // 16 MB
    _Float16* WqThi = (_Float16*)(ws + 112 * MB);  // 2 MB each, Wq/Wk adjacent
    _Float16* WqTlo = (_Float16*)(ws + 114 * MB);
    // PV split-K partials (alias dead Qhi..Klo): 2 x 32 MB fp32
    float* PK0 = (float*)(ws + 16 * MB);

    const size_t rowBytes = (size_t)Nt * 4;  // 32 KB per S row
    const bool planA = ws_size >= 208 * MB + 128 * rowBytes;
    _Float16* Pbuf = (_Float16*)(ws + 80 * MB);   // plan A: 128 MB compact P

    // 1. prep: one pass over X -> Xhi,Xlo,XT; both weight transposes fused
    prep_x<<<dim3(32, 256), dim3(32, 8), 0, stream>>>(X, Xhi, Xlo, XT,
                                                      (int)Nt, (int)D);
    transpose_split2<<<dim3(32, 32, 2), dim3(32, 8), 0, stream>>>(
        Wq, Wk, WqThi, WqTlo, (int)D, (int)D, (long)(4 * MB / 2));

    // 2. fused Q+K projections (3-term split), z=0 -> Q, z=1 -> K.
    //    zB = WkThi-WqThi = 4 MB = 2M halves; zC = Khi-Qhi = 16M halves.
    //    1024 blocks at 4/CU -> fully resident.
    gemm_bt<3, 1, 1, 32><<<dim3(Nt / TM, D / TN, 2), 256, 0, stream>>>(
        Xhi, Xlo, WqThi, WqTlo, nullptr, Qhi, Qlo, D, D, D, (int)D,
        0, (long)(4 * MB / 2), (long)(32 * MB / 2));

    if (planA) {
        float* Sc = (float*)(ws + 208 * MB);
        size_t avail = ws_size - 208 * MB;
        long chunk = (long)((avail / rowBytes / 128) * 128);
        if (chunk > Nt) chunk = Nt;
        long nch = (Nt + chunk - 1) / chunk;
        chunk = (((Nt + nch - 1) / nch) + 127) / 128 * 128;

        // 3. serial chunks: S = Q@K^T (SWAP=0: 64 col-blocks = K-splits
        //    XCD-co-located), then softmax -> compact P f16. Serial is the
        //    measured best: all fusion variants starve the GEMM (R9/R10).
        long done = 0;
        while (done < Nt) {
            long cur = Nt - done < chunk ? Nt - done : chunk;
            gemm_bt<3, 0, 0, 32>
                <<<dim3(Nt / TN, cur / TM, 1), 256, 0, stream>>>(
                Qhi + done * D, Qlo + done * D, Khi, Klo, Sc, nullptr, nullptr,
                D, D, Nt, (int)D, 0, 0, 0);
            softmax_rows<<<(int)cur, 256, 0, stream>>>(
                Sc, Pbuf + done * Nt, Nt, (int)Nt);
            done += cur;
        }

        // 4. PV split-K=2, BK=64, SWAP=1 (measured best: grid (64,8,2) ->
        //    id%8 = row-block%8, P row-tile co-located per XCD; 0 LDS
        //    conflicts; 1024 blocks -> 4/CU). Partials PK0/PK1 in the dead
        //    Q/K region, then one add pass (atomics measured -63us, R11).
        gemm_bt<1, 0, 1, 64><<<dim3(Nt / TM, D / TN, 2), 256, 0, stream>>>(
            Pbuf, nullptr, XT, nullptr, PK0, nullptr, nullptr,
            Nt, Nt, D, (int)(Nt / 2),
            Nt / 2, Nt / 2, Nt * D);
        add_rows<<<1024, 256, 0, stream>>>(PK0, PK0 + Nt * D, out, Nt * D / 4);
    } else {
        // Plan B (small ws): serial chunks, in-place P, per-chunk PV.
        float* Sc = (float*)(ws + 80 * MB);
        size_t avail = ws_size > 80 * MB ? ws_size - 80 * MB : 0;
        long chunk = (long)((avail / rowBytes / 128) * 128);
        if (chunk < 128) chunk = 128;
        if (chunk > Nt) chunk = Nt;
        long nch = (Nt + chunk - 1) / chunk;
        chunk = (((Nt + nch - 1) / nch) + 127) / 128 * 128;
        long done = 0;
        while (done < Nt) {
            long cur = Nt - done < chunk ? Nt - done : chunk;
            gemm_bt<3, 0, 0, 32>
                <<<dim3(Nt / TN, cur / TM, 1), 256, 0, stream>>>(
                Qhi + done * D, Qlo + done * D, Khi, Klo, Sc, nullptr, nullptr,
                D, D, Nt, (int)D, 0, 0, 0);
            softmax_rows<<<(int)cur, 256, 0, stream>>>(Sc, (_Float16*)Sc,
                                                       2 * Nt, (int)Nt);
            gemm_bt<1, 0, 1, 64>
                <<<dim3(cur / TM, D / TN, 1), 256, 0, stream>>>(
                (const _Float16*)Sc, nullptr, XT, nullptr,
                out + done * D, nullptr, nullptr, 2 * Nt, Nt, D, (int)Nt,
                0, 0, 0);
            done += cur;
        }
    }
}